// Round 13
// baseline (152.895 us; speedup 1.0000x reference)
//
#include <hip/hip_runtime.h>

#define SQ 4096      // sequence length = 64*64
#define CCH 256      // channels
#define NH 8         // heads
#define HD 32        // head dim
#define LN_EPS 1e-5f
#define NSPLIT 4     // kv splits per head
#define VROWS 48     // V^T rows per head: 32 data + 16 pad (row32=ones, rest 0)

typedef __bf16 bf16x8 __attribute__((ext_vector_type(8)));
typedef float f32x4 __attribute__((ext_vector_type(4)));
using bf16 = __bf16;

// Raw hardware 2^x (exp2f lowers to a ~20-VALU OCML guarded sequence;
// inputs here are bounded so the fixups are dead weight).
__device__ __forceinline__ float fast_exp2(float x) {
#if defined(__has_builtin)
#if __has_builtin(__builtin_amdgcn_exp2f)
    return __builtin_amdgcn_exp2f(x);
#else
    float r;
    asm("v_exp_f32 %0, %1" : "=v"(r) : "v"(x));
    return r;
#endif
#else
    float r;
    asm("v_exp_f32 %0, %1" : "=v"(r) : "v"(x));
    return r;
#endif
}

// ---------------------------------------------------------------------------
// Tile transpose + fp32->bf16 convert: src [R][Ccol] f32 -> dst [Ccol][R] bf16
// ---------------------------------------------------------------------------
__device__ __forceinline__ void tile_tc(const float* __restrict__ src, bf16* __restrict__ dst,
                                        int R, int Ccol, int ti, int tj) {
    __shared__ float t[32][33];
    const int tx = threadIdx.x & 31;
    const int ty = threadIdx.x >> 5;   // 0..7
    const int i0 = ti * 32, j0 = tj * 32;
    #pragma unroll
    for (int i = 0; i < 32; i += 8)
        t[ty + i][tx] = src[(size_t)(i0 + ty + i) * Ccol + j0 + tx];
    __syncthreads();
    #pragma unroll
    for (int i = 0; i < 32; i += 8)
        dst[(size_t)(j0 + ty + i) * R + i0 + tx] = (bf16)t[tx][ty + i];
}

// ---------------------------------------------------------------------------
// ALL conversions in one launch (2880 blocks):
// id<2048: inputs x,y [C][S] f32 -> [S][C] bf16; else weights + vT pad init.
// ---------------------------------------------------------------------------
__global__ __launch_bounds__(256)
void cvt_all(const float* __restrict__ x, const float* __restrict__ y,
             bf16* __restrict__ xT, bf16* __restrict__ yT,
             const float* Wq, const float* Wk, const float* Wv, const float* Wo,
             const float* W1, const float* W2,
             bf16* WqT, bf16* WkT, bf16* WvT, bf16* WoT, bf16* W1T, bf16* W2T,
             bf16* vTb) {
    const int id = blockIdx.x;
    if (id < 2048) {
        const int z = id >> 10;
        const int t = id & 1023;
        const float* s = z ? y : x;
        bf16* d = z ? yT : xT;
        tile_tc(s, d, CCH, SQ, t >> 7, t & 127);
        return;
    }
    const int wid = id - 2048;
    if (wid < 256) {
        const int w = wid >> 6, local = wid & 63;
        const float* s = (w == 0) ? Wq : (w == 1) ? Wk : (w == 2) ? Wv : Wo;
        bf16* d = (w == 0) ? WqT : (w == 1) ? WkT : (w == 2) ? WvT : WoT;
        tile_tc(s, d, 256, 256, local >> 3, local & 7);
    } else if (wid < 512) {
        const int local = wid - 256;
        tile_tc(W1, W1T, 256, 1024, local >> 5, local & 31);
    } else if (wid < 768) {
        const int local = wid - 512;
        tile_tc(W2, W2T, 1024, 256, local >> 3, local & 7);
    } else {
        // init vT pad rows: per head rows 32..47 -> row 32 = 1.0, rest 0
        const int local = wid - 768;         // 0..63
        #pragma unroll
        for (int rr = 0; rr < 2; ++rr) {
            const int pr = local * 2 + rr;   // 0..127
            const int hh = pr >> 4, j = pr & 15;
            const bf16 val = (bf16)((j == 0) ? 1.0f : 0.0f);
            bf16x8 v8;
            #pragma unroll
            for (int e = 0; e < 8; ++e) v8[e] = val;
            bf16* dst = vTb + ((size_t)hh * VROWS + 32 + j) * SQ + threadIdx.x * 16;
            *reinterpret_cast<bf16x8*>(dst) = v8;
            *reinterpret_cast<bf16x8*>(dst + 8) = v8;
        }
    }
}

// ---------------------------------------------------------------------------
// 8-wave MFMA GEMM: 512 threads, 64x64 tile, wave w -> 16x32 sub-tile.
// 2-4x the resident waves/CU of the 4-wave version: these GEMMs are
// latency-bound on L2-resident fragment loads, so TLP is the lever.
// OUT_MODE: 0 = f32; 2 = bf16.
// ---------------------------------------------------------------------------
template <int K, int OUT_MODE, bool RELU>
__global__ __launch_bounds__(512)
void gemm_mfma(const bf16* __restrict__ A, const bf16* __restrict__ BT,
               const float* __restrict__ bias, float* __restrict__ Cf,
               bf16* __restrict__ Cb, int N) {
    const int tid = threadIdx.x;
    const int w = tid >> 6, l = tid & 63;
    const int l15 = l & 15, lg = l >> 4;
    const int m0 = blockIdx.x * 64 + (w >> 1) * 16;
    const int n0 = blockIdx.y * 64 + (w & 1) * 32;

    f32x4 acc[2] = {};
    const bf16* a0 = &A[(size_t)(m0 + l15) * K + lg * 8];
    const bf16* b0 = &BT[(size_t)(n0 + l15) * K + lg * 8];

    for (int k0 = 0; k0 < K; k0 += 32) {
        bf16x8 a = *reinterpret_cast<const bf16x8*>(a0 + k0);
        bf16x8 b[2];
        b[0] = *reinterpret_cast<const bf16x8*>(b0 + k0);
        b[1] = *reinterpret_cast<const bf16x8*>(b0 + (size_t)16 * K + k0);
        #pragma unroll
        for (int j = 0; j < 2; ++j)
            acc[j] = __builtin_amdgcn_mfma_f32_16x16x32_bf16(a, b[j], acc[j], 0, 0, 0);
    }

    #pragma unroll
    for (int j = 0; j < 2; ++j) {
        const int col = n0 + j * 16 + l15;
        const float bs = bias[col];
        #pragma unroll
        for (int r = 0; r < 4; ++r) {
            const int row = m0 + lg * 4 + r;
            float val = acc[j][r] + bs;
            if (RELU) val = fmaxf(val, 0.f);
            if constexpr (OUT_MODE == 0)
                Cf[(size_t)row * N + col] = val;
            if constexpr (OUT_MODE == 2)
                Cb[(size_t)row * N + col] = (bf16)val;
        }
    }
}

// ---------------------------------------------------------------------------
// 8-wave split-K GEMM: z = k-slice; f32 partial at Cf + z*SQ*N.
// ---------------------------------------------------------------------------
template <int K, int KS>
__global__ __launch_bounds__(512)
void gemm_sk(const bf16* __restrict__ A, const bf16* __restrict__ BT,
             const float* __restrict__ bias, float* __restrict__ Cf, int N) {
    constexpr int KSL = K / KS;
    const int z = blockIdx.z;
    const int tid = threadIdx.x;
    const int w = tid >> 6, l = tid & 63;
    const int l15 = l & 15, lg = l >> 4;
    const int m0 = blockIdx.x * 64 + (w >> 1) * 16;
    const int n0 = blockIdx.y * 64 + (w & 1) * 32;

    f32x4 acc[2] = {};
    const bf16* a0 = &A[(size_t)(m0 + l15) * K + z * KSL + lg * 8];
    const bf16* b0 = &BT[(size_t)(n0 + l15) * K + z * KSL + lg * 8];

    for (int k0 = 0; k0 < KSL; k0 += 32) {
        bf16x8 a = *reinterpret_cast<const bf16x8*>(a0 + k0);
        bf16x8 b[2];
        b[0] = *reinterpret_cast<const bf16x8*>(b0 + k0);
        b[1] = *reinterpret_cast<const bf16x8*>(b0 + (size_t)16 * K + k0);
        #pragma unroll
        for (int j = 0; j < 2; ++j)
            acc[j] = __builtin_amdgcn_mfma_f32_16x16x32_bf16(a, b[j], acc[j], 0, 0, 0);
    }

    float* C = Cf + (size_t)z * SQ * N;
    #pragma unroll
    for (int j = 0; j < 2; ++j) {
        const int col = n0 + j * 16 + l15;
        const float bs = (z == 0) ? bias[col] : 0.f;
        #pragma unroll
        for (int r = 0; r < 4; ++r) {
            const int row = m0 + lg * 4 + r;
            C[(size_t)row * N + col] = acc[j][r] + bs;
        }
    }
}

// ---------------------------------------------------------------------------
// 8-wave fused QKV projections: grid z = 0(q) / 1(k) / 2(v).
// v written transposed into the padded [NH*48][SQ] layout.
// ---------------------------------------------------------------------------
__global__ __launch_bounds__(512)
void qkv_gemm(const bf16* __restrict__ xT, const bf16* __restrict__ yT,
              const bf16* __restrict__ WqT, const bf16* __restrict__ WkT,
              const bf16* __restrict__ WvT,
              const float* __restrict__ bq, const float* __restrict__ bk,
              const float* __restrict__ bv,
              bf16* __restrict__ qb, bf16* __restrict__ kbb, bf16* __restrict__ vTb,
              float kscale) {
    const int z = blockIdx.z;
    const bf16* A  = (z == 0) ? xT : yT;
    const bf16* BT = (z == 0) ? WqT : (z == 1) ? WkT : WvT;
    const float* bias = (z == 0) ? bq : (z == 1) ? bk : bv;

    const int tid = threadIdx.x;
    const int w = tid >> 6, l = tid & 63;
    const int l15 = l & 15, lg = l >> 4;
    const int m0 = blockIdx.x * 64 + (w >> 1) * 16;
    const int n0 = blockIdx.y * 64 + (w & 1) * 32;

    f32x4 acc[2] = {};
    const bf16* a0 = &A[(size_t)(m0 + l15) * CCH + lg * 8];
    const bf16* b0 = &BT[(size_t)(n0 + l15) * CCH + lg * 8];

    for (int k0 = 0; k0 < CCH; k0 += 32) {
        bf16x8 a = *reinterpret_cast<const bf16x8*>(a0 + k0);
        bf16x8 b[2];
        b[0] = *reinterpret_cast<const bf16x8*>(b0 + k0);
        b[1] = *reinterpret_cast<const bf16x8*>(b0 + (size_t)16 * CCH + k0);
        #pragma unroll
        for (int j = 0; j < 2; ++j)
            acc[j] = __builtin_amdgcn_mfma_f32_16x16x32_bf16(a, b[j], acc[j], 0, 0, 0);
    }

    const float sc = (z == 1) ? kscale : 1.f;
    #pragma unroll
    for (int j = 0; j < 2; ++j) {
        const int col = n0 + j * 16 + l15;
        const float bs = bias[col];
        #pragma unroll
        for (int r = 0; r < 4; ++r) {
            const int row = m0 + lg * 4 + r;
            float val = acc[j][r] + bs;
            if (z == 2)
                vTb[((size_t)(col >> 5) * VROWS + (col & 31)) * SQ + row] = (bf16)val;
            else if (z == 1)
                kbb[(size_t)row * CCH + col] = (bf16)(val * sc);
            else
                qb[(size_t)row * CCH + col] = (bf16)val;
        }
    }
}

// ---------------------------------------------------------------------------
// MFMA flash attention v11 (unchanged from r12): quad-Q, swapped QK^T,
// no-max softmax, MFMA row-sum via ones-row, raw v_exp_f32.
// ---------------------------------------------------------------------------
__global__ __launch_bounds__(256)
void flash_attn11(const bf16* __restrict__ qb, const bf16* __restrict__ kb,
                  const bf16* __restrict__ vT, bf16* __restrict__ Op,
                  float* __restrict__ Lp) {
    const int fid = blockIdx.x + 16 * (blockIdx.y + NH * blockIdx.z);
    const int nid = (fid & 7) * 64 + (fid >> 3);
    const int q0 = (nid & 15) * 256;
    const int h  = (nid >> 4) & 7;
    const int sp = nid >> 7;

    const int tid = threadIdx.x;
    const int w = tid >> 6, l = tid & 63;
    const int l15 = l & 15, lg = l >> 4;

    __shared__ unsigned int Sb[4][2][8][72];   // [wave][parity][slot][lane] 18KB

    bf16x8 aq[4];
    #pragma unroll
    for (int su = 0; su < 4; ++su)
        aq[su] = *reinterpret_cast<const bf16x8*>(
            &qb[(size_t)(q0 + su * 64 + w * 16 + l15) * CCH + h * HD + lg * 8]);

    f32x4 o[4][2] = {};
    f32x4 o2[4] = {};   // row-sum accumulators (ones-row MFMA)

    const bf16* kfrag = &kb[(size_t)l15 * CCH + h * HD + lg * 8];
    const bf16* vfrag = &vT[((size_t)h * VROWS + l15) * SQ + lg * 8];

    const int kt0 = sp * (SQ / NSPLIT / 64);
    const int kt1 = kt0 + (SQ / NSPLIT / 64);

    for (int kt = kt0; kt < kt1; ++kt) {
        const int kb0 = kt * 64;

        bf16x8 kf[4], vf[3][2];
        #pragma unroll
        for (int t = 0; t < 4; ++t)
            kf[t] = *reinterpret_cast<const bf16x8*>(kfrag + (size_t)(kb0 + t * 16) * CCH);
        #pragma unroll
        for (int dh = 0; dh < 3; ++dh)
            #pragma unroll
            for (int kh = 0; kh < 2; ++kh)
                vf[dh][kh] = *reinterpret_cast<const bf16x8*>(
                    vfrag + (size_t)dh * 16 * SQ + kb0 + kh * 32);

        #pragma unroll
        for (int su = 0; su < 4; ++su) {
            const int par = su & 1;
            f32x4 s[4];
            #pragma unroll
            for (int t = 0; t < 4; ++t)
                s[t] = __builtin_amdgcn_mfma_f32_16x16x32_bf16(
                    kf[t], aq[su], (f32x4){0.f, 0.f, 0.f, 0.f}, 0, 0, 0);

            #pragma unroll
            for (int t = 0; t < 4; ++t) {
                unsigned int u0 = __builtin_bit_cast(unsigned int, fast_exp2(s[t][0]));
                unsigned int u1 = __builtin_bit_cast(unsigned int, fast_exp2(s[t][1]));
                unsigned int u2 = __builtin_bit_cast(unsigned int, fast_exp2(s[t][2]));
                unsigned int u3 = __builtin_bit_cast(unsigned int, fast_exp2(s[t][3]));
                Sb[w][par][t * 2 + 0][l] = __builtin_amdgcn_perm(u1, u0, 0x07060302u);
                Sb[w][par][t * 2 + 1][l] = __builtin_amdgcn_perm(u3, u2, 0x07060302u);
            }

            #pragma unroll
            for (int kh = 0; kh < 2; ++kh) {
                const int sbase = kh * 4 + (lg >> 1) * 2;
                const int i0 = l15 + 16 * ((lg & 1) * 2);
                const int i1 = i0 + 16;
                union { unsigned int u[4]; bf16x8 v; } pb;
                pb.u[0] = Sb[w][par][sbase + 0][i0];
                pb.u[1] = Sb[w][par][sbase + 1][i0];
                pb.u[2] = Sb[w][par][sbase + 0][i1];
                pb.u[3] = Sb[w][par][sbase + 1][i1];
                #pragma unroll
                for (int dh = 0; dh < 2; ++dh)
                    o[su][dh] = __builtin_amdgcn_mfma_f32_16x16x32_bf16(
                        vf[dh][kh], pb.v, o[su][dh], 0, 0, 0);
                o2[su] = __builtin_amdgcn_mfma_f32_16x16x32_bf16(
                    vf[2][kh], pb.v, o2[su], 0, 0, 0);
            }
        }
    }

    const size_t obase = ((size_t)sp * NH + h) * HD;
    #pragma unroll
    for (int su = 0; su < 4; ++su) {
        const int qrow = q0 + su * 64 + w * 16 + l15;
        #pragma unroll
        for (int dh = 0; dh < 2; ++dh)
            #pragma unroll
            for (int r = 0; r < 4; ++r)
                Op[(obase + dh * 16 + lg * 4 + r) * SQ + qrow] = (bf16)o[su][dh][r];
        if (lg == 0)
            Lp[((size_t)sp * NH + h) * SQ + qrow] = o2[su][0];
    }
}

// ---------------------------------------------------------------------------
// Merge NSPLIT raw partial O^T [d][q] tiles -> atb [S][C] bf16.
// ---------------------------------------------------------------------------
__global__ __launch_bounds__(256)
void attn_merge3(const bf16* __restrict__ Op, const float* __restrict__ Lp,
                 bf16* __restrict__ atb) {
    const int h = blockIdx.y;
    const int q0 = blockIdx.x * 64;
    const int t = threadIdx.x;
    __shared__ float sInv[64];
    __shared__ float trans[32][65];

    if (t < 64) {
        float L = 0.f;
        #pragma unroll
        for (int sp = 0; sp < NSPLIT; ++sp)
            L += Lp[((size_t)sp * NH + h) * SQ + q0 + t];
        sInv[t] = 1.0f / L;
    }
    __syncthreads();

    const int q = t & 63, dg = t >> 6;
    float a[8] = {0.f, 0.f, 0.f, 0.f, 0.f, 0.f, 0.f, 0.f};
    for (int sp = 0; sp < NSPLIT; ++sp) {
        const size_t rb = ((size_t)sp * NH + h) * HD;
        #pragma unroll
        for (int i = 0; i < 8; ++i) {
            const int d = i * 4 + dg;
            a[i] += (float)Op[(rb + d) * SQ + q0 + q];
        }
    }
    const float invq = sInv[q];
    #pragma unroll
    for (int i = 0; i < 8; ++i)
        trans[i * 4 + dg][q] = a[i] * invq;
    __syncthreads();

    const int oq = t >> 2, od = (t & 3) * 8;
    bf16x8 o8;
    #pragma unroll
    for (int j = 0; j < 8; ++j) o8[j] = (bf16)trans[od + j][oq];
    *reinterpret_cast<bf16x8*>(&atb[(size_t)(q0 + oq) * CCH + h * HD + od]) = o8;
}

// ---------------------------------------------------------------------------
// LN1: residual (bf16 q) + TWO f32 partials of Wo -> f32 + bf16 outputs.
// ---------------------------------------------------------------------------
__global__ __launch_bounds__(256)
void add_ln1(const bf16* __restrict__ a, const float* __restrict__ b,
             const float* __restrict__ g, const float* __restrict__ beta,
             float* __restrict__ out, bf16* __restrict__ outb) {
    const int s = blockIdx.x;
    const int c = threadIdx.x;
    const size_t idx = (size_t)s * CCH + c;
    float val = (float)a[idx] + b[idx] + b[idx + (size_t)SQ * CCH];
    float sum = val, sq = val * val;
    #pragma unroll
    for (int off = 1; off < 64; off <<= 1) {
        sum += __shfl_xor(sum, off);
        sq  += __shfl_xor(sq, off);
    }
    __shared__ float ssum[4], ssq[4];
    int w = c >> 6;
    if ((c & 63) == 0) { ssum[w] = sum; ssq[w] = sq; }
    __syncthreads();
    sum = ssum[0] + ssum[1] + ssum[2] + ssum[3];
    sq  = ssq[0] + ssq[1] + ssq[2] + ssq[3];
    float mu = sum * (1.0f / CCH);
    float var = sq * (1.0f / CCH) - mu * mu;
    float rs = rsqrtf(var + LN_EPS);
    float res = (val - mu) * rs * g[c] + beta[c];
    out[idx] = res;
    outb[idx] = (bf16)res;
}

// ---------------------------------------------------------------------------
// LN2 (residual + TWO f32 FFN2 partials) fused with final transpose to [C][S].
// ---------------------------------------------------------------------------
__global__ __launch_bounds__(256)
void add_ln_t(const float* __restrict__ a, const float* __restrict__ b,
              const float* __restrict__ g, const float* __restrict__ beta,
              float* __restrict__ out) {
    const int s0 = blockIdx.x * 32;
    const int t = threadIdx.x;
    const int row = t >> 3;
    const int e8 = t & 7;
    const size_t base = (size_t)(s0 + row) * CCH + e8 * 32;
    const size_t PS = (size_t)SQ * CCH;

    float v[32];
    float sum = 0.f, sq = 0.f;
    #pragma unroll
    for (int j = 0; j < 32; j += 4) {
        float4 va = *reinterpret_cast<const float4*>(&a[base + j]);
        float4 vb = *reinterpret_cast<const float4*>(&b[base + j]);
        float4 vc = *reinterpret_cast<const float4*>(&b[base + PS + j]);
        v[j]     = va.x + vb.x + vc.x;
        v[j + 1] = va.y + vb.y + vc.y;
        v[j + 2] = va.z + vb.z + vc.z;
        v[j + 3] = va.w + vb.w + vc.w;
        sum += (v[j] + v[j + 1]) + (v[j + 2] + v[j + 3]);
        sq  += (v[j] * v[j] + v[j + 1] * v[j + 1]) + (v[j + 2] * v[j + 2] + v[j + 3] * v[j + 3]);
    }
    sum += __shfl_xor(sum, 1); sum += __shfl_xor(sum, 2); sum += __shfl_xor(sum, 4);
    sq  += __shfl_xor(sq, 1);  sq  += __shfl_xor(sq, 2);  sq  += __shfl_xor(sq, 4);
    const float mu = sum * (1.0f / CCH);
    const float var = sq * (1.0f / CCH) - mu * mu;
    const float rs = rsqrtf(var + LN_EPS);
    #pragma unroll
    for (int j = 0; j < 32; j += 4) {
        float4 gg = *reinterpret_cast<const float4*>(&g[e8 * 32 + j]);
        float4 bb = *reinterpret_cast<const float4*>(&beta[e8 * 32 + j]);
        v[j]     = (v[j]     - mu) * rs * gg.x + bb.x;
        v[j + 1] = (v[j + 1] - mu) * rs * gg.y + bb.y;
        v[j + 2] = (v[j + 2] - mu) * rs * gg.z + bb.z;
        v[j + 3] = (v[j + 3] - mu) * rs * gg.w + bb.w;
    }

    __shared__ float tile[32][33];
    const int cl = t >> 3, f4 = (t & 7) * 4;
    for (int c = 0; c < 8; ++c) {
        __syncthreads();
        if (e8 == c) {
            #pragma unroll
            for (int j = 0; j < 32; ++j) tile[j][row] = v[j];
        }
        __syncthreads();
        float4 o4 = {tile[cl][f4], tile[cl][f4 + 1], tile[cl][f4 + 2], tile[cl][f4 + 3]};
        *reinterpret_cast<float4*>(&out[(size_t)(c * 32 + cl) * SQ + s0 + f4]) = o4;
    }
}

// ---------------------------------------------------------------------------
extern "C" void kernel_launch(void* const* d_in, const int* in_sizes, int n_in,
                              void* d_out, int out_size, void* d_ws, size_t ws_size,
                              hipStream_t stream) {
    const float* lidar = (const float*)d_in[0];
    const float* image = (const float*)d_in[1];
    const float* Wq  = (const float*)d_in[2];
    const float* bq  = (const float*)d_in[3];
    const float* Wk  = (const float*)d_in[4];
    const float* bk  = (const float*)d_in[5];
    const float* Wv  = (const float*)d_in[6];
    const float* bv  = (const float*)d_in[7];
    const float* Wo  = (const float*)d_in[8];
    const float* bo  = (const float*)d_in[9];
    const float* g1  = (const float*)d_in[10];
    const float* b1  = (const float*)d_in[11];
    const float* W1  = (const float*)d_in[12];
    const float* bf1 = (const float*)d_in[13];
    const float* W2  = (const float*)d_in[14];
    const float* bf2 = (const float*)d_in[15];
    const float* g2  = (const float*)d_in[16];
    const float* b2  = (const float*)d_in[17];
    float* out = (float*)d_out;

    // workspace layout (aliased; peak 23.5 MB).  Lp (512K) in d_out until merge.
    char* ws = (char*)d_ws;
    const size_t KB = 1024;
    bf16* W2T = (bf16*)(ws + 0);                 // [0,512K)     live -> ffn2
    bf16* W1T = (bf16*)(ws + 512 * KB);          // [512K,1M)    live -> ffn1
    bf16* WoT = (bf16*)(ws + 1024 * KB);         // [1,1.125M)   live -> Wo
    bf16* WqT = (bf16*)(ws + 1152 * KB);         // dead after qkv
    bf16* WkT = (bf16*)(ws + 1280 * KB);
    bf16* WvT = (bf16*)(ws + 1408 * KB);         // ends 1.5M
    bf16* qb  = (bf16*)(ws + 1536 * KB);         // [1.5,3.5M)   live -> ln1
    bf16* kbb = (bf16*)(ws + 3584 * KB);         // [3.5,5.5M)   dead after flash
    bf16* vTb = (bf16*)(ws + 5632 * KB);         // [5.5,8.5M)   padded; dead after flash
    bf16* xT  = (bf16*)(ws + 8704 * KB);         // [8.5,10.5M)  dead after qkv
    bf16* yT  = (bf16*)(ws + 10752 * KB);        // [10.5,12.5M) dead after qkv
    bf16* Op  = (bf16*)(ws + 8704 * KB);         // [8.5,16.5M)  overlays xT/yT
    float* Lp = (float*)d_out;                   // 512K scratch in d_out
    bf16* atb = (bf16*)(ws + 3584 * KB);         // reuses kbb; dead after Wo
    float* o01 = (float*)(ws + 8704 * KB);       // [8.5,16.5M)  2 partials; dead after ln1
    float* ln1 = (float*)(ws + 19968 * KB);      // [19.5,23.5M) live -> ln_t
    bf16* ln1b = (bf16*)(ws + 5632 * KB);        // [5.5,7.5M)   reuses vTb; dead after ffn1
    bf16* h1  = (bf16*)(ws + 9728 * KB);         // [9.5,17.5M)  dead after ffn2
    float* h2 = (float*)(ws + 1536 * KB);        // [1.5,9.5M)   2 partials; qb/kbb/vTb dead

    // 1/sqrt(32) * log2(e) folded into K -> scores already in log2 domain
    const float qscale = 0.17677669529663687f * 1.4426950408889634f;
    dim3 blk(256), blk8(512);

    // all layout conversions in one launch
    cvt_all<<<dim3(2880), blk, 0, stream>>>(lidar, image, xT, yT,
                                            Wq, Wk, Wv, Wo, W1, W2,
                                            WqT, WkT, WvT, WoT, W1T, W2T, vTb);
    // fused QKV projections (8-wave blocks)
    qkv_gemm<<<dim3(64, 4, 3), blk8, 0, stream>>>(xT, yT, WqT, WkT, WvT,
                                                  bq, bk, bv, qb, kbb, vTb, qscale);
    // attention (split-KV x4, swapped-operand, no-max, MFMA row-sum, v_exp)
    flash_attn11<<<dim3(SQ / 256, NH, NSPLIT), blk, 0, stream>>>(qb, kbb, vTb, Op, Lp);
    attn_merge3<<<dim3(SQ / 64, NH), blk, 0, stream>>>(Op, Lp, atb);
    // output projection, split-K=2 (8-wave)
    gemm_sk<256, 2><<<dim3(64, 4, 2), blk8, 0, stream>>>(atb, WoT, bo, o01, 256);
    // LN1(q + o0 + o1) -> f32 + bf16
    add_ln1<<<SQ, blk, 0, stream>>>(qb, o01, g1, b1, ln1, ln1b);
    // FFN (8-wave)
    gemm_mfma<256, 2, true><<<dim3(64, 16), blk8, 0, stream>>>(ln1b, W1T, bf1, nullptr, h1, 1024);
    gemm_sk<1024, 2><<<dim3(64, 4, 2), blk8, 0, stream>>>(h1, W2T, bf2, h2, 256);
    // LN2(ln1 + h2_0 + h2_1) fused with final [S][C] -> [C][S] transpose
    add_ln_t<<<dim3(SQ / 32), blk, 0, stream>>>(ln1, h2, g2, b2, out);
}

// Round 14
// 128.667 us; speedup vs baseline: 1.1883x; 1.1883x over previous
//
#include <hip/hip_runtime.h>

#define SQ 4096      // sequence length = 64*64
#define CCH 256      // channels
#define NH 8         // heads
#define HD 32        // head dim
#define LN_EPS 1e-5f
#define NSPLIT 4     // kv splits per head
#define VROWS 48     // V^T rows per head: 32 data + 16 pad (row32=ones, rest 0)

typedef __bf16 bf16x8 __attribute__((ext_vector_type(8)));
typedef float f32x4 __attribute__((ext_vector_type(4)));
using bf16 = __bf16;

// Raw hardware 2^x (exp2f lowers to a ~20-VALU OCML guarded sequence;
// inputs here are bounded so the fixups are dead weight).
__device__ __forceinline__ float fast_exp2(float x) {
#if defined(__has_builtin)
#if __has_builtin(__builtin_amdgcn_exp2f)
    return __builtin_amdgcn_exp2f(x);
#else
    float r;
    asm("v_exp_f32 %0, %1" : "=v"(r) : "v"(x));
    return r;
#endif
#else
    float r;
    asm("v_exp_f32 %0, %1" : "=v"(r) : "v"(x));
    return r;
#endif
}

// ---------------------------------------------------------------------------
// Tile transpose + fp32->bf16 convert: src [R][Ccol] f32 -> dst [Ccol][R] bf16
// ---------------------------------------------------------------------------
__device__ __forceinline__ void tile_tc(const float* __restrict__ src, bf16* __restrict__ dst,
                                        int R, int Ccol, int ti, int tj) {
    __shared__ float t[32][33];
    const int tx = threadIdx.x & 31;
    const int ty = threadIdx.x >> 5;   // 0..7
    const int i0 = ti * 32, j0 = tj * 32;
    #pragma unroll
    for (int i = 0; i < 32; i += 8)
        t[ty + i][tx] = src[(size_t)(i0 + ty + i) * Ccol + j0 + tx];
    __syncthreads();
    #pragma unroll
    for (int i = 0; i < 32; i += 8)
        dst[(size_t)(j0 + ty + i) * R + i0 + tx] = (bf16)t[tx][ty + i];
}

// ---------------------------------------------------------------------------
// ALL conversions in one launch (2880 blocks).
// ---------------------------------------------------------------------------
__global__ __launch_bounds__(256)
void cvt_all(const float* __restrict__ x, const float* __restrict__ y,
             bf16* __restrict__ xT, bf16* __restrict__ yT,
             const float* Wq, const float* Wk, const float* Wv, const float* Wo,
             const float* W1, const float* W2,
             bf16* WqT, bf16* WkT, bf16* WvT, bf16* WoT, bf16* W1T, bf16* W2T,
             bf16* vTb) {
    const int id = blockIdx.x;
    if (id < 2048) {
        const int z = id >> 10;
        const int t = id & 1023;
        const float* s = z ? y : x;
        bf16* d = z ? yT : xT;
        tile_tc(s, d, CCH, SQ, t >> 7, t & 127);
        return;
    }
    const int wid = id - 2048;
    if (wid < 256) {
        const int w = wid >> 6, local = wid & 63;
        const float* s = (w == 0) ? Wq : (w == 1) ? Wk : (w == 2) ? Wv : Wo;
        bf16* d = (w == 0) ? WqT : (w == 1) ? WkT : (w == 2) ? WvT : WoT;
        tile_tc(s, d, 256, 256, local >> 3, local & 7);
    } else if (wid < 512) {
        const int local = wid - 256;
        tile_tc(W1, W1T, 256, 1024, local >> 5, local & 31);
    } else if (wid < 768) {
        const int local = wid - 512;
        tile_tc(W2, W2T, 1024, 256, local >> 3, local & 7);
    } else {
        // init vT pad rows: per head rows 32..47 -> row 32 = 1.0, rest 0
        const int local = wid - 768;         // 0..63
        #pragma unroll
        for (int rr = 0; rr < 2; ++rr) {
            const int pr = local * 2 + rr;   // 0..127
            const int hh = pr >> 4, j = pr & 15;
            const bf16 val = (bf16)((j == 0) ? 1.0f : 0.0f);
            bf16x8 v8;
            #pragma unroll
            for (int e = 0; e < 8; ++e) v8[e] = val;
            bf16* dst = vTb + ((size_t)hh * VROWS + 32 + j) * SQ + threadIdx.x * 16;
            *reinterpret_cast<bf16x8*>(dst) = v8;
            *reinterpret_cast<bf16x8*>(dst + 8) = v8;
        }
    }
}

// ---------------------------------------------------------------------------
// 4-wave MFMA GEMM (r12 version): 64x64 tile, wave -> 32x32, reg fragments.
// OUT_MODE: 0 = f32; 2 = bf16.
// ---------------------------------------------------------------------------
template <int K, int OUT_MODE, bool RELU>
__global__ __launch_bounds__(256)
void gemm_mfma(const bf16* __restrict__ A, const bf16* __restrict__ BT,
               const float* __restrict__ bias, float* __restrict__ Cf,
               bf16* __restrict__ Cb, int N) {
    const int tid = threadIdx.x;
    const int w = tid >> 6, l = tid & 63;
    const int l15 = l & 15, lg = l >> 4;
    const int m0 = blockIdx.x * 64 + (w >> 1) * 32;
    const int n0 = blockIdx.y * 64 + (w & 1) * 32;

    f32x4 acc[2][2] = {};
    const bf16* a0 = &A[(size_t)(m0 + l15) * K + lg * 8];
    const bf16* b0 = &BT[(size_t)(n0 + l15) * K + lg * 8];

    for (int k0 = 0; k0 < K; k0 += 32) {
        bf16x8 a[2], b[2];
        a[0] = *reinterpret_cast<const bf16x8*>(a0 + k0);
        a[1] = *reinterpret_cast<const bf16x8*>(a0 + (size_t)16 * K + k0);
        b[0] = *reinterpret_cast<const bf16x8*>(b0 + k0);
        b[1] = *reinterpret_cast<const bf16x8*>(b0 + (size_t)16 * K + k0);
        #pragma unroll
        for (int i = 0; i < 2; ++i)
            #pragma unroll
            for (int j = 0; j < 2; ++j)
                acc[i][j] = __builtin_amdgcn_mfma_f32_16x16x32_bf16(a[i], b[j], acc[i][j], 0, 0, 0);
    }

    #pragma unroll
    for (int i = 0; i < 2; ++i) {
        #pragma unroll
        for (int j = 0; j < 2; ++j) {
            const int col = n0 + j * 16 + l15;
            const float bs = bias[col];
            #pragma unroll
            for (int r = 0; r < 4; ++r) {
                const int row = m0 + i * 16 + lg * 4 + r;
                float val = acc[i][j][r] + bs;
                if (RELU) val = fmaxf(val, 0.f);
                if constexpr (OUT_MODE == 0)
                    Cf[(size_t)row * N + col] = val;
                if constexpr (OUT_MODE == 2)
                    Cb[(size_t)row * N + col] = (bf16)val;
            }
        }
    }
}

// ---------------------------------------------------------------------------
// 4-wave split-K GEMM (r12 version): z = k-slice; f32 partial at Cf + z*SQ*N.
// ---------------------------------------------------------------------------
template <int K, int KS>
__global__ __launch_bounds__(256)
void gemm_sk(const bf16* __restrict__ A, const bf16* __restrict__ BT,
             const float* __restrict__ bias, float* __restrict__ Cf, int N) {
    constexpr int KSL = K / KS;
    const int z = blockIdx.z;
    const int tid = threadIdx.x;
    const int w = tid >> 6, l = tid & 63;
    const int l15 = l & 15, lg = l >> 4;
    const int m0 = blockIdx.x * 64 + (w >> 1) * 32;
    const int n0 = blockIdx.y * 64 + (w & 1) * 32;

    f32x4 acc[2][2] = {};
    const bf16* a0 = &A[(size_t)(m0 + l15) * K + z * KSL + lg * 8];
    const bf16* b0 = &BT[(size_t)(n0 + l15) * K + z * KSL + lg * 8];

    for (int k0 = 0; k0 < KSL; k0 += 32) {
        bf16x8 a[2], b[2];
        a[0] = *reinterpret_cast<const bf16x8*>(a0 + k0);
        a[1] = *reinterpret_cast<const bf16x8*>(a0 + (size_t)16 * K + k0);
        b[0] = *reinterpret_cast<const bf16x8*>(b0 + k0);
        b[1] = *reinterpret_cast<const bf16x8*>(b0 + (size_t)16 * K + k0);
        #pragma unroll
        for (int i = 0; i < 2; ++i)
            #pragma unroll
            for (int j = 0; j < 2; ++j)
                acc[i][j] = __builtin_amdgcn_mfma_f32_16x16x32_bf16(a[i], b[j], acc[i][j], 0, 0, 0);
    }

    float* C = Cf + (size_t)z * SQ * N;
    #pragma unroll
    for (int i = 0; i < 2; ++i) {
        #pragma unroll
        for (int j = 0; j < 2; ++j) {
            const int col = n0 + j * 16 + l15;
            const float bs = (z == 0) ? bias[col] : 0.f;
            #pragma unroll
            for (int r = 0; r < 4; ++r) {
                const int row = m0 + i * 16 + lg * 4 + r;
                C[(size_t)row * N + col] = acc[i][j][r] + bs;
            }
        }
    }
}

// ---------------------------------------------------------------------------
// 4-wave fused QKV projections (r12 version): grid z = 0(q) / 1(k) / 2(v).
// ---------------------------------------------------------------------------
__global__ __launch_bounds__(256)
void qkv_gemm(const bf16* __restrict__ xT, const bf16* __restrict__ yT,
              const bf16* __restrict__ WqT, const bf16* __restrict__ WkT,
              const bf16* __restrict__ WvT,
              const float* __restrict__ bq, const float* __restrict__ bk,
              const float* __restrict__ bv,
              bf16* __restrict__ qb, bf16* __restrict__ kbb, bf16* __restrict__ vTb,
              float kscale) {
    const int z = blockIdx.z;
    const bf16* A  = (z == 0) ? xT : yT;
    const bf16* BT = (z == 0) ? WqT : (z == 1) ? WkT : WvT;
    const float* bias = (z == 0) ? bq : (z == 1) ? bk : bv;

    const int tid = threadIdx.x;
    const int w = tid >> 6, l = tid & 63;
    const int l15 = l & 15, lg = l >> 4;
    const int m0 = blockIdx.x * 64 + (w >> 1) * 32;
    const int n0 = blockIdx.y * 64 + (w & 1) * 32;

    f32x4 acc[2][2] = {};
    const bf16* a0 = &A[(size_t)(m0 + l15) * CCH + lg * 8];
    const bf16* b0 = &BT[(size_t)(n0 + l15) * CCH + lg * 8];

    for (int k0 = 0; k0 < CCH; k0 += 32) {
        bf16x8 a[2], b[2];
        a[0] = *reinterpret_cast<const bf16x8*>(a0 + k0);
        a[1] = *reinterpret_cast<const bf16x8*>(a0 + (size_t)16 * CCH + k0);
        b[0] = *reinterpret_cast<const bf16x8*>(b0 + k0);
        b[1] = *reinterpret_cast<const bf16x8*>(b0 + (size_t)16 * CCH + k0);
        #pragma unroll
        for (int i = 0; i < 2; ++i)
            #pragma unroll
            for (int j = 0; j < 2; ++j)
                acc[i][j] = __builtin_amdgcn_mfma_f32_16x16x32_bf16(a[i], b[j], acc[i][j], 0, 0, 0);
    }

    const float sc = (z == 1) ? kscale : 1.f;
    #pragma unroll
    for (int i = 0; i < 2; ++i) {
        #pragma unroll
        for (int j = 0; j < 2; ++j) {
            const int col = n0 + j * 16 + l15;
            const float bs = bias[col];
            #pragma unroll
            for (int r = 0; r < 4; ++r) {
                const int row = m0 + i * 16 + lg * 4 + r;
                float val = acc[i][j][r] + bs;
                if (z == 2)
                    vTb[((size_t)(col >> 5) * VROWS + (col & 31)) * SQ + row] = (bf16)val;
                else if (z == 1)
                    kbb[(size_t)row * CCH + col] = (bf16)(val * sc);
                else
                    qb[(size_t)row * CCH + col] = (bf16)val;
            }
        }
    }
}

// ---------------------------------------------------------------------------
// Fused Wo projection + residual + LN1, row-panel form: block = 16 rows x
// all 256 cols (wave w owns a 64-col panel; K=256).  Whole rows in-block ->
// LayerNorm reduction via 16-lane shfl + tiny LDS cross-wave combine.
// Replaces the split-K Wo GEMM (8MB f32 write) + add_ln1 (18MB read).
// ---------------------------------------------------------------------------
__global__ __launch_bounds__(256)
void wo_ln1(const bf16* __restrict__ atb, const bf16* __restrict__ WoT,
            const float* __restrict__ bo, const bf16* __restrict__ qb,
            const float* __restrict__ g, const float* __restrict__ beta,
            float* __restrict__ ln1, bf16* __restrict__ ln1b) {
    const int tid = threadIdx.x;
    const int w = tid >> 6, l = tid & 63;
    const int l15 = l & 15, lg = l >> 4;
    const int mr = blockIdx.x * 16;
    const int n0 = w * 64;

    f32x4 acc[4] = {};
    const bf16* a0 = &atb[(size_t)(mr + l15) * CCH + lg * 8];
    const bf16* b0 = &WoT[(size_t)(n0 + l15) * CCH + lg * 8];
    #pragma unroll
    for (int k0 = 0; k0 < CCH; k0 += 32) {
        bf16x8 a = *reinterpret_cast<const bf16x8*>(a0 + k0);
        #pragma unroll
        for (int j = 0; j < 4; ++j) {
            bf16x8 b = *reinterpret_cast<const bf16x8*>(b0 + (size_t)j * 16 * CCH + k0);
            acc[j] = __builtin_amdgcn_mfma_f32_16x16x32_bf16(a, b, acc[j], 0, 0, 0);
        }
    }

    // values + bias + residual; per-row partial stats
    float val[4][4];
    float rsum[4] = {0.f, 0.f, 0.f, 0.f}, rsq[4] = {0.f, 0.f, 0.f, 0.f};
    #pragma unroll
    for (int j = 0; j < 4; ++j) {
        const int col = n0 + j * 16 + l15;
        const float bs = bo[col];
        #pragma unroll
        for (int r = 0; r < 4; ++r) {
            const int row = mr + lg * 4 + r;
            float v = acc[j][r] + bs + (float)qb[(size_t)row * CCH + col];
            val[j][r] = v;
            rsum[r] += v;
            rsq[r] += v * v;
        }
    }
    // reduce across the 16 lanes of each row group
    #pragma unroll
    for (int r = 0; r < 4; ++r) {
        #pragma unroll
        for (int off = 1; off < 16; off <<= 1) {
            rsum[r] += __shfl_xor(rsum[r], off);
            rsq[r]  += __shfl_xor(rsq[r], off);
        }
    }
    __shared__ float ssum[4][16], ssq[4][16];
    if (l15 == 0) {
        #pragma unroll
        for (int r = 0; r < 4; ++r) {
            ssum[w][lg * 4 + r] = rsum[r];
            ssq[w][lg * 4 + r]  = rsq[r];
        }
    }
    __syncthreads();
    float mu_[4], rs_[4];
    #pragma unroll
    for (int r = 0; r < 4; ++r) {
        const int row = lg * 4 + r;
        float s = (ssum[0][row] + ssum[1][row]) + (ssum[2][row] + ssum[3][row]);
        float q = (ssq[0][row] + ssq[1][row]) + (ssq[2][row] + ssq[3][row]);
        float mu = s * (1.0f / CCH);
        float var = q * (1.0f / CCH) - mu * mu;
        mu_[r] = mu;
        rs_[r] = rsqrtf(var + LN_EPS);
    }
    #pragma unroll
    for (int j = 0; j < 4; ++j) {
        const int col = n0 + j * 16 + l15;
        const float gg = g[col], bb = beta[col];
        #pragma unroll
        for (int r = 0; r < 4; ++r) {
            const int row = mr + lg * 4 + r;
            float res = (val[j][r] - mu_[r]) * rs_[r] * gg + bb;
            ln1[(size_t)row * CCH + col] = res;
            ln1b[(size_t)row * CCH + col] = (bf16)res;
        }
    }
}

// ---------------------------------------------------------------------------
// MFMA flash attention v11 (unchanged): quad-Q, swapped QK^T, no-max softmax,
// MFMA row-sum via ones-row, raw v_exp_f32.
// ---------------------------------------------------------------------------
__global__ __launch_bounds__(256)
void flash_attn11(const bf16* __restrict__ qb, const bf16* __restrict__ kb,
                  const bf16* __restrict__ vT, bf16* __restrict__ Op,
                  float* __restrict__ Lp) {
    const int fid = blockIdx.x + 16 * (blockIdx.y + NH * blockIdx.z);
    const int nid = (fid & 7) * 64 + (fid >> 3);
    const int q0 = (nid & 15) * 256;
    const int h  = (nid >> 4) & 7;
    const int sp = nid >> 7;

    const int tid = threadIdx.x;
    const int w = tid >> 6, l = tid & 63;
    const int l15 = l & 15, lg = l >> 4;

    __shared__ unsigned int Sb[4][2][8][72];   // [wave][parity][slot][lane] 18KB

    bf16x8 aq[4];
    #pragma unroll
    for (int su = 0; su < 4; ++su)
        aq[su] = *reinterpret_cast<const bf16x8*>(
            &qb[(size_t)(q0 + su * 64 + w * 16 + l15) * CCH + h * HD + lg * 8]);

    f32x4 o[4][2] = {};
    f32x4 o2[4] = {};   // row-sum accumulators (ones-row MFMA)

    const bf16* kfrag = &kb[(size_t)l15 * CCH + h * HD + lg * 8];
    const bf16* vfrag = &vT[((size_t)h * VROWS + l15) * SQ + lg * 8];

    const int kt0 = sp * (SQ / NSPLIT / 64);
    const int kt1 = kt0 + (SQ / NSPLIT / 64);

    for (int kt = kt0; kt < kt1; ++kt) {
        const int kb0 = kt * 64;

        bf16x8 kf[4], vf[3][2];
        #pragma unroll
        for (int t = 0; t < 4; ++t)
            kf[t] = *reinterpret_cast<const bf16x8*>(kfrag + (size_t)(kb0 + t * 16) * CCH);
        #pragma unroll
        for (int dh = 0; dh < 3; ++dh)
            #pragma unroll
            for (int kh = 0; kh < 2; ++kh)
                vf[dh][kh] = *reinterpret_cast<const bf16x8*>(
                    vfrag + (size_t)dh * 16 * SQ + kb0 + kh * 32);

        #pragma unroll
        for (int su = 0; su < 4; ++su) {
            const int par = su & 1;
            f32x4 s[4];
            #pragma unroll
            for (int t = 0; t < 4; ++t)
                s[t] = __builtin_amdgcn_mfma_f32_16x16x32_bf16(
                    kf[t], aq[su], (f32x4){0.f, 0.f, 0.f, 0.f}, 0, 0, 0);

            #pragma unroll
            for (int t = 0; t < 4; ++t) {
                unsigned int u0 = __builtin_bit_cast(unsigned int, fast_exp2(s[t][0]));
                unsigned int u1 = __builtin_bit_cast(unsigned int, fast_exp2(s[t][1]));
                unsigned int u2 = __builtin_bit_cast(unsigned int, fast_exp2(s[t][2]));
                unsigned int u3 = __builtin_bit_cast(unsigned int, fast_exp2(s[t][3]));
                Sb[w][par][t * 2 + 0][l] = __builtin_amdgcn_perm(u1, u0, 0x07060302u);
                Sb[w][par][t * 2 + 1][l] = __builtin_amdgcn_perm(u3, u2, 0x07060302u);
            }

            #pragma unroll
            for (int kh = 0; kh < 2; ++kh) {
                const int sbase = kh * 4 + (lg >> 1) * 2;
                const int i0 = l15 + 16 * ((lg & 1) * 2);
                const int i1 = i0 + 16;
                union { unsigned int u[4]; bf16x8 v; } pb;
                pb.u[0] = Sb[w][par][sbase + 0][i0];
                pb.u[1] = Sb[w][par][sbase + 1][i0];
                pb.u[2] = Sb[w][par][sbase + 0][i1];
                pb.u[3] = Sb[w][par][sbase + 1][i1];
                #pragma unroll
                for (int dh = 0; dh < 2; ++dh)
                    o[su][dh] = __builtin_amdgcn_mfma_f32_16x16x32_bf16(
                        vf[dh][kh], pb.v, o[su][dh], 0, 0, 0);
                o2[su] = __builtin_amdgcn_mfma_f32_16x16x32_bf16(
                    vf[2][kh], pb.v, o2[su], 0, 0, 0);
            }
        }
    }

    const size_t obase = ((size_t)sp * NH + h) * HD;
    #pragma unroll
    for (int su = 0; su < 4; ++su) {
        const int qrow = q0 + su * 64 + w * 16 + l15;
        #pragma unroll
        for (int dh = 0; dh < 2; ++dh)
            #pragma unroll
            for (int r = 0; r < 4; ++r)
                Op[(obase + dh * 16 + lg * 4 + r) * SQ + qrow] = (bf16)o[su][dh][r];
        if (lg == 0)
            Lp[((size_t)sp * NH + h) * SQ + qrow] = o2[su][0];
    }
}

// ---------------------------------------------------------------------------
// Merge NSPLIT raw partial O^T [d][q] tiles -> atb [S][C] bf16.
// ---------------------------------------------------------------------------
__global__ __launch_bounds__(256)
void attn_merge3(const bf16* __restrict__ Op, const float* __restrict__ Lp,
                 bf16* __restrict__ atb) {
    const int h = blockIdx.y;
    const int q0 = blockIdx.x * 64;
    const int t = threadIdx.x;
    __shared__ float sInv[64];
    __shared__ float trans[32][65];

    if (t < 64) {
        float L = 0.f;
        #pragma unroll
        for (int sp = 0; sp < NSPLIT; ++sp)
            L += Lp[((size_t)sp * NH + h) * SQ + q0 + t];
        sInv[t] = 1.0f / L;
    }
    __syncthreads();

    const int q = t & 63, dg = t >> 6;
    float a[8] = {0.f, 0.f, 0.f, 0.f, 0.f, 0.f, 0.f, 0.f};
    for (int sp = 0; sp < NSPLIT; ++sp) {
        const size_t rb = ((size_t)sp * NH + h) * HD;
        #pragma unroll
        for (int i = 0; i < 8; ++i) {
            const int d = i * 4 + dg;
            a[i] += (float)Op[(rb + d) * SQ + q0 + q];
        }
    }
    const float invq = sInv[q];
    #pragma unroll
    for (int i = 0; i < 8; ++i)
        trans[i * 4 + dg][q] = a[i] * invq;
    __syncthreads();

    const int oq = t >> 2, od = (t & 3) * 8;
    bf16x8 o8;
    #pragma unroll
    for (int j = 0; j < 8; ++j) o8[j] = (bf16)trans[od + j][oq];
    *reinterpret_cast<bf16x8*>(&atb[(size_t)(q0 + oq) * CCH + h * HD + od]) = o8;
}

// ---------------------------------------------------------------------------
// LN2 (residual + TWO f32 FFN2 partials) fused with final transpose to [C][S].
// ---------------------------------------------------------------------------
__global__ __launch_bounds__(256)
void add_ln_t(const float* __restrict__ a, const float* __restrict__ b,
              const float* __restrict__ g, const float* __restrict__ beta,
              float* __restrict__ out) {
    const int s0 = blockIdx.x * 32;
    const int t = threadIdx.x;
    const int row = t >> 3;
    const int e8 = t & 7;
    const size_t base = (size_t)(s0 + row) * CCH + e8 * 32;
    const size_t PS = (size_t)SQ * CCH;

    float v[32];
    float sum = 0.f, sq = 0.f;
    #pragma unroll
    for (int j = 0; j < 32; j += 4) {
        float4 va = *reinterpret_cast<const float4*>(&a[base + j]);
        float4 vb = *reinterpret_cast<const float4*>(&b[base + j]);
        float4 vc = *reinterpret_cast<const float4*>(&b[base + PS + j]);
        v[j]     = va.x + vb.x + vc.x;
        v[j + 1] = va.y + vb.y + vc.y;
        v[j + 2] = va.z + vb.z + vc.z;
        v[j + 3] = va.w + vb.w + vc.w;
        sum += (v[j] + v[j + 1]) + (v[j + 2] + v[j + 3]);
        sq  += (v[j] * v[j] + v[j + 1] * v[j + 1]) + (v[j + 2] * v[j + 2] + v[j + 3] * v[j + 3]);
    }
    sum += __shfl_xor(sum, 1); sum += __shfl_xor(sum, 2); sum += __shfl_xor(sum, 4);
    sq  += __shfl_xor(sq, 1);  sq  += __shfl_xor(sq, 2);  sq  += __shfl_xor(sq, 4);
    const float mu = sum * (1.0f / CCH);
    const float var = sq * (1.0f / CCH) - mu * mu;
    const float rs = rsqrtf(var + LN_EPS);
    #pragma unroll
    for (int j = 0; j < 32; j += 4) {
        float4 gg = *reinterpret_cast<const float4*>(&g[e8 * 32 + j]);
        float4 bb = *reinterpret_cast<const float4*>(&beta[e8 * 32 + j]);
        v[j]     = (v[j]     - mu) * rs * gg.x + bb.x;
        v[j + 1] = (v[j + 1] - mu) * rs * gg.y + bb.y;
        v[j + 2] = (v[j + 2] - mu) * rs * gg.z + bb.z;
        v[j + 3] = (v[j + 3] - mu) * rs * gg.w + bb.w;
    }

    __shared__ float tile[32][33];
    const int cl = t >> 3, f4 = (t & 7) * 4;
    for (int c = 0; c < 8; ++c) {
        __syncthreads();
        if (e8 == c) {
            #pragma unroll
            for (int j = 0; j < 32; ++j) tile[j][row] = v[j];
        }
        __syncthreads();
        float4 o4 = {tile[cl][f4], tile[cl][f4 + 1], tile[cl][f4 + 2], tile[cl][f4 + 3]};
        *reinterpret_cast<float4*>(&out[(size_t)(c * 32 + cl) * SQ + s0 + f4]) = o4;
    }
}

// ---------------------------------------------------------------------------
extern "C" void kernel_launch(void* const* d_in, const int* in_sizes, int n_in,
                              void* d_out, int out_size, void* d_ws, size_t ws_size,
                              hipStream_t stream) {
    const float* lidar = (const float*)d_in[0];
    const float* image = (const float*)d_in[1];
    const float* Wq  = (const float*)d_in[2];
    const float* bq  = (const float*)d_in[3];
    const float* Wk  = (const float*)d_in[4];
    const float* bk  = (const float*)d_in[5];
    const float* Wv  = (const float*)d_in[6];
    const float* bv  = (const float*)d_in[7];
    const float* Wo  = (const float*)d_in[8];
    const float* bo  = (const float*)d_in[9];
    const float* g1  = (const float*)d_in[10];
    const float* b1  = (const float*)d_in[11];
    const float* W1  = (const float*)d_in[12];
    const float* bf1 = (const float*)d_in[13];
    const float* W2  = (const float*)d_in[14];
    const float* bf2 = (const float*)d_in[15];
    const float* g2  = (const float*)d_in[16];
    const float* b2  = (const float*)d_in[17];
    float* out = (float*)d_out;

    // workspace layout (aliased; peak 23.5 MB).  Lp (512K) in d_out until merge.
    char* ws = (char*)d_ws;
    const size_t KB = 1024;
    bf16* W2T = (bf16*)(ws + 0);                 // [0,512K)     live -> ffn2
    bf16* W1T = (bf16*)(ws + 512 * KB);          // [512K,1M)    live -> ffn1
    bf16* WoT = (bf16*)(ws + 1024 * KB);         // [1,1.125M)   live -> wo_ln1
    bf16* WqT = (bf16*)(ws + 1152 * KB);         // dead after qkv
    bf16* WkT = (bf16*)(ws + 1280 * KB);
    bf16* WvT = (bf16*)(ws + 1408 * KB);         // ends 1.5M
    bf16* qb  = (bf16*)(ws + 1536 * KB);         // [1.5,3.5M)   live -> wo_ln1
    bf16* kbb = (bf16*)(ws + 3584 * KB);         // [3.5,5.5M)   dead after flash
    bf16* vTb = (bf16*)(ws + 5632 * KB);         // [5.5,8.5M)   padded; dead after flash
    bf16* xT  = (bf16*)(ws + 8704 * KB);         // [8.5,10.5M)  dead after qkv
    bf16* yT  = (bf16*)(ws + 10752 * KB);        // [10.5,12.5M) dead after qkv
    bf16* Op  = (bf16*)(ws + 8704 * KB);         // [8.5,16.5M)  overlays xT/yT
    float* Lp = (float*)d_out;                   // 512K scratch in d_out
    bf16* atb = (bf16*)(ws + 3584 * KB);         // reuses kbb; dead after wo_ln1
    float* ln1 = (float*)(ws + 19968 * KB);      // [19.5,23.5M) live -> ln_t
    bf16* ln1b = (bf16*)(ws + 5632 * KB);        // [5.5,7.5M)   reuses vTb; dead after ffn1
    bf16* h1  = (bf16*)(ws + 9728 * KB);         // [9.5,17.5M)  dead after ffn2
    float* h2 = (float*)(ws + 1536 * KB);        // [1.5,9.5M)   2 partials; qb/kbb/vTb dead

    // 1/sqrt(32) * log2(e) folded into K -> scores already in log2 domain
    const float qscale = 0.17677669529663687f * 1.4426950408889634f;
    dim3 blk(256);

    // all layout conversions in one launch
    cvt_all<<<dim3(2880), blk, 0, stream>>>(lidar, image, xT, yT,
                                            Wq, Wk, Wv, Wo, W1, W2,
                                            WqT, WkT, WvT, WoT, W1T, W2T, vTb);
    // fused QKV projections
    qkv_gemm<<<dim3(64, 4, 3), blk, 0, stream>>>(xT, yT, WqT, WkT, WvT,
                                                 bq, bk, bv, qb, kbb, vTb, qscale);
    // attention (split-KV x4, swapped-operand, no-max, MFMA row-sum, v_exp)
    flash_attn11<<<dim3(SQ / 256, NH, NSPLIT), blk, 0, stream>>>(qb, kbb, vTb, Op, Lp);
    attn_merge3<<<dim3(SQ / 64, NH), blk, 0, stream>>>(Op, Lp, atb);
    // fused Wo projection + residual + LN1 (row-panel)
    wo_ln1<<<dim3(SQ / 16), blk, 0, stream>>>(atb, WoT, bo, qb, g1, b1, ln1, ln1b);
    // FFN
    gemm_mfma<256, 2, true><<<dim3(64, 16), blk, 0, stream>>>(ln1b, W1T, bf1, nullptr, h1, 1024);
    gemm_sk<1024, 2><<<dim3(64, 4, 2), blk, 0, stream>>>(h1, W2T, bf2, h2, 256);
    // LN2(ln1 + h2_0 + h2_1) fused with final [S][C] -> [C][S] transpose
    add_ln_t<<<dim3(SQ / 32), blk, 0, stream>>>(ln1, h2, g2, b2, out);
}

// Round 15
// 120.583 us; speedup vs baseline: 1.2680x; 1.0670x over previous
//
#include <hip/hip_runtime.h>

#define SQ 4096      // sequence length = 64*64
#define CCH 256      // channels
#define NH 8         // heads
#define HD 32        // head dim
#define LN_EPS 1e-5f
#define NSPLIT 4     // kv splits per head
#define VROWS 48     // V^T rows per head: 32 data + 16 pad (row32=ones, rest 0)

typedef __bf16 bf16x8 __attribute__((ext_vector_type(8)));
typedef float f32x4 __attribute__((ext_vector_type(4)));
using bf16 = __bf16;

// Raw hardware 2^x (exp2f lowers to a ~20-VALU OCML guarded sequence;
// inputs here are bounded so the fixups are dead weight).
__device__ __forceinline__ float fast_exp2(float x) {
#if defined(__has_builtin)
#if __has_builtin(__builtin_amdgcn_exp2f)
    return __builtin_amdgcn_exp2f(x);
#else
    float r;
    asm("v_exp_f32 %0, %1" : "=v"(r) : "v"(x));
    return r;
#endif
#else
    float r;
    asm("v_exp_f32 %0, %1" : "=v"(r) : "v"(x));
    return r;
#endif
}

// ---------------------------------------------------------------------------
// Tile transpose + fp32->bf16 convert: src [R][Ccol] f32 -> dst [Ccol][R] bf16
// ---------------------------------------------------------------------------
__device__ __forceinline__ void tile_tc(const float* __restrict__ src, bf16* __restrict__ dst,
                                        int R, int Ccol, int ti, int tj) {
    __shared__ float t[32][33];
    const int tx = threadIdx.x & 31;
    const int ty = threadIdx.x >> 5;   // 0..7
    const int i0 = ti * 32, j0 = tj * 32;
    #pragma unroll
    for (int i = 0; i < 32; i += 8)
        t[ty + i][tx] = src[(size_t)(i0 + ty + i) * Ccol + j0 + tx];
    __syncthreads();
    #pragma unroll
    for (int i = 0; i < 32; i += 8)
        dst[(size_t)(j0 + ty + i) * R + i0 + tx] = (bf16)t[tx][ty + i];
}

// ---------------------------------------------------------------------------
// ALL conversions in one launch (2880 blocks).
// ---------------------------------------------------------------------------
__global__ __launch_bounds__(256)
void cvt_all(const float* __restrict__ x, const float* __restrict__ y,
             bf16* __restrict__ xT, bf16* __restrict__ yT,
             const float* Wq, const float* Wk, const float* Wv, const float* Wo,
             const float* W1, const float* W2,
             bf16* WqT, bf16* WkT, bf16* WvT, bf16* WoT, bf16* W1T, bf16* W2T,
             bf16* vTb) {
    const int id = blockIdx.x;
    if (id < 2048) {
        const int z = id >> 10;
        const int t = id & 1023;
        const float* s = z ? y : x;
        bf16* d = z ? yT : xT;
        tile_tc(s, d, CCH, SQ, t >> 7, t & 127);
        return;
    }
    const int wid = id - 2048;
    if (wid < 256) {
        const int w = wid >> 6, local = wid & 63;
        const float* s = (w == 0) ? Wq : (w == 1) ? Wk : (w == 2) ? Wv : Wo;
        bf16* d = (w == 0) ? WqT : (w == 1) ? WkT : (w == 2) ? WvT : WoT;
        tile_tc(s, d, 256, 256, local >> 3, local & 7);
    } else if (wid < 512) {
        const int local = wid - 256;
        tile_tc(W1, W1T, 256, 1024, local >> 5, local & 31);
    } else if (wid < 768) {
        const int local = wid - 512;
        tile_tc(W2, W2T, 1024, 256, local >> 3, local & 7);
    } else {
        // init vT pad rows: per head rows 32..47 -> row 32 = 1.0, rest 0
        const int local = wid - 768;         // 0..63
        #pragma unroll
        for (int rr = 0; rr < 2; ++rr) {
            const int pr = local * 2 + rr;   // 0..127
            const int hh = pr >> 4, j = pr & 15;
            const bf16 val = (bf16)((j == 0) ? 1.0f : 0.0f);
            bf16x8 v8;
            #pragma unroll
            for (int e = 0; e < 8; ++e) v8[e] = val;
            bf16* dst = vTb + ((size_t)hh * VROWS + 32 + j) * SQ + threadIdx.x * 16;
            *reinterpret_cast<bf16x8*>(dst) = v8;
            *reinterpret_cast<bf16x8*>(dst + 8) = v8;
        }
    }
}

// ---------------------------------------------------------------------------
// 4-wave MFMA GEMM: 64x64 tile, wave -> 32x32, reg fragments.
// OUT_MODE: 0 = f32; 2 = bf16.
// ---------------------------------------------------------------------------
template <int K, int OUT_MODE, bool RELU>
__global__ __launch_bounds__(256)
void gemm_mfma(const bf16* __restrict__ A, const bf16* __restrict__ BT,
               const float* __restrict__ bias, float* __restrict__ Cf,
               bf16* __restrict__ Cb, int N) {
    const int tid = threadIdx.x;
    const int w = tid >> 6, l = tid & 63;
    const int l15 = l & 15, lg = l >> 4;
    const int m0 = blockIdx.x * 64 + (w >> 1) * 32;
    const int n0 = blockIdx.y * 64 + (w & 1) * 32;

    f32x4 acc[2][2] = {};
    const bf16* a0 = &A[(size_t)(m0 + l15) * K + lg * 8];
    const bf16* b0 = &BT[(size_t)(n0 + l15) * K + lg * 8];

    for (int k0 = 0; k0 < K; k0 += 32) {
        bf16x8 a[2], b[2];
        a[0] = *reinterpret_cast<const bf16x8*>(a0 + k0);
        a[1] = *reinterpret_cast<const bf16x8*>(a0 + (size_t)16 * K + k0);
        b[0] = *reinterpret_cast<const bf16x8*>(b0 + k0);
        b[1] = *reinterpret_cast<const bf16x8*>(b0 + (size_t)16 * K + k0);
        #pragma unroll
        for (int i = 0; i < 2; ++i)
            #pragma unroll
            for (int j = 0; j < 2; ++j)
                acc[i][j] = __builtin_amdgcn_mfma_f32_16x16x32_bf16(a[i], b[j], acc[i][j], 0, 0, 0);
    }

    #pragma unroll
    for (int i = 0; i < 2; ++i) {
        #pragma unroll
        for (int j = 0; j < 2; ++j) {
            const int col = n0 + j * 16 + l15;
            const float bs = bias[col];
            #pragma unroll
            for (int r = 0; r < 4; ++r) {
                const int row = m0 + i * 16 + lg * 4 + r;
                float val = acc[i][j][r] + bs;
                if (RELU) val = fmaxf(val, 0.f);
                if constexpr (OUT_MODE == 0)
                    Cf[(size_t)row * N + col] = val;
                if constexpr (OUT_MODE == 2)
                    Cb[(size_t)row * N + col] = (bf16)val;
            }
        }
    }
}

// ---------------------------------------------------------------------------
// 4-wave fused QKV projections: grid z = 0(q) / 1(k) / 2(v).
// ---------------------------------------------------------------------------
__global__ __launch_bounds__(256)
void qkv_gemm(const bf16* __restrict__ xT, const bf16* __restrict__ yT,
              const bf16* __restrict__ WqT, const bf16* __restrict__ WkT,
              const bf16* __restrict__ WvT,
              const float* __restrict__ bq, const float* __restrict__ bk,
              const float* __restrict__ bv,
              bf16* __restrict__ qb, bf16* __restrict__ kbb, bf16* __restrict__ vTb,
              float kscale) {
    const int z = blockIdx.z;
    const bf16* A  = (z == 0) ? xT : yT;
    const bf16* BT = (z == 0) ? WqT : (z == 1) ? WkT : WvT;
    const float* bias = (z == 0) ? bq : (z == 1) ? bk : bv;

    const int tid = threadIdx.x;
    const int w = tid >> 6, l = tid & 63;
    const int l15 = l & 15, lg = l >> 4;
    const int m0 = blockIdx.x * 64 + (w >> 1) * 32;
    const int n0 = blockIdx.y * 64 + (w & 1) * 32;

    f32x4 acc[2][2] = {};
    const bf16* a0 = &A[(size_t)(m0 + l15) * CCH + lg * 8];
    const bf16* b0 = &BT[(size_t)(n0 + l15) * CCH + lg * 8];

    for (int k0 = 0; k0 < CCH; k0 += 32) {
        bf16x8 a[2], b[2];
        a[0] = *reinterpret_cast<const bf16x8*>(a0 + k0);
        a[1] = *reinterpret_cast<const bf16x8*>(a0 + (size_t)16 * CCH + k0);
        b[0] = *reinterpret_cast<const bf16x8*>(b0 + k0);
        b[1] = *reinterpret_cast<const bf16x8*>(b0 + (size_t)16 * CCH + k0);
        #pragma unroll
        for (int i = 0; i < 2; ++i)
            #pragma unroll
            for (int j = 0; j < 2; ++j)
                acc[i][j] = __builtin_amdgcn_mfma_f32_16x16x32_bf16(a[i], b[j], acc[i][j], 0, 0, 0);
    }

    const float sc = (z == 1) ? kscale : 1.f;
    #pragma unroll
    for (int i = 0; i < 2; ++i) {
        #pragma unroll
        for (int j = 0; j < 2; ++j) {
            const int col = n0 + j * 16 + l15;
            const float bs = bias[col];
            #pragma unroll
            for (int r = 0; r < 4; ++r) {
                const int row = m0 + i * 16 + lg * 4 + r;
                float val = acc[i][j][r] + bs;
                if (z == 2)
                    vTb[((size_t)(col >> 5) * VROWS + (col & 31)) * SQ + row] = (bf16)val;
                else if (z == 1)
                    kbb[(size_t)row * CCH + col] = (bf16)(val * sc);
                else
                    qb[(size_t)row * CCH + col] = (bf16)val;
            }
        }
    }
}

// ---------------------------------------------------------------------------
// Fused Wo projection + residual + LN1, row-panel form (proven in r14).
// ---------------------------------------------------------------------------
__global__ __launch_bounds__(256)
void wo_ln1(const bf16* __restrict__ atb, const bf16* __restrict__ WoT,
            const float* __restrict__ bo, const bf16* __restrict__ qb,
            const float* __restrict__ g, const float* __restrict__ beta,
            float* __restrict__ ln1, bf16* __restrict__ ln1b) {
    const int tid = threadIdx.x;
    const int w = tid >> 6, l = tid & 63;
    const int l15 = l & 15, lg = l >> 4;
    const int mr = blockIdx.x * 16;
    const int n0 = w * 64;

    f32x4 acc[4] = {};
    const bf16* a0 = &atb[(size_t)(mr + l15) * CCH + lg * 8];
    const bf16* b0 = &WoT[(size_t)(n0 + l15) * CCH + lg * 8];
    #pragma unroll
    for (int k0 = 0; k0 < CCH; k0 += 32) {
        bf16x8 a = *reinterpret_cast<const bf16x8*>(a0 + k0);
        #pragma unroll
        for (int j = 0; j < 4; ++j) {
            bf16x8 b = *reinterpret_cast<const bf16x8*>(b0 + (size_t)j * 16 * CCH + k0);
            acc[j] = __builtin_amdgcn_mfma_f32_16x16x32_bf16(a, b, acc[j], 0, 0, 0);
        }
    }

    float val[4][4];
    float rsum[4] = {0.f, 0.f, 0.f, 0.f}, rsq[4] = {0.f, 0.f, 0.f, 0.f};
    #pragma unroll
    for (int j = 0; j < 4; ++j) {
        const int col = n0 + j * 16 + l15;
        const float bs = bo[col];
        #pragma unroll
        for (int r = 0; r < 4; ++r) {
            const int row = mr + lg * 4 + r;
            float v = acc[j][r] + bs + (float)qb[(size_t)row * CCH + col];
            val[j][r] = v;
            rsum[r] += v;
            rsq[r] += v * v;
        }
    }
    #pragma unroll
    for (int r = 0; r < 4; ++r) {
        #pragma unroll
        for (int off = 1; off < 16; off <<= 1) {
            rsum[r] += __shfl_xor(rsum[r], off);
            rsq[r]  += __shfl_xor(rsq[r], off);
        }
    }
    __shared__ float ssum[4][16], ssq[4][16];
    if (l15 == 0) {
        #pragma unroll
        for (int r = 0; r < 4; ++r) {
            ssum[w][lg * 4 + r] = rsum[r];
            ssq[w][lg * 4 + r]  = rsq[r];
        }
    }
    __syncthreads();
    float mu_[4], rs_[4];
    #pragma unroll
    for (int r = 0; r < 4; ++r) {
        const int row = lg * 4 + r;
        float s = (ssum[0][row] + ssum[1][row]) + (ssum[2][row] + ssum[3][row]);
        float q = (ssq[0][row] + ssq[1][row]) + (ssq[2][row] + ssq[3][row]);
        float mu = s * (1.0f / CCH);
        float var = q * (1.0f / CCH) - mu * mu;
        mu_[r] = mu;
        rs_[r] = rsqrtf(var + LN_EPS);
    }
    #pragma unroll
    for (int j = 0; j < 4; ++j) {
        const int col = n0 + j * 16 + l15;
        const float gg = g[col], bb = beta[col];
        #pragma unroll
        for (int r = 0; r < 4; ++r) {
            const int row = mr + lg * 4 + r;
            float res = (val[j][r] - mu_[r]) * rs_[r] * gg + bb;
            ln1[(size_t)row * CCH + col] = res;
            ln1b[(size_t)row * CCH + col] = (bf16)res;
        }
    }
}

// ---------------------------------------------------------------------------
// Fused FFN2 + residual + LN2 + output transpose, row-panel form.
// Block = 16 rows x 256 cols, K=1024; wave w -> 64-col panel.  LN2 stats
// via 16-lane shfl + LDS cross-wave combine; final [S][C]->[C][S] transpose
// through a [256][17]-padded LDS tile (<=2-way bank aliasing everywhere).
// Replaces split-K FFN2 (16.8MB f32 write) + add_ln_t (28MB read).
// ---------------------------------------------------------------------------
__global__ __launch_bounds__(256)
void ffn2_ln2_t(const bf16* __restrict__ h1, const bf16* __restrict__ W2T,
                const float* __restrict__ bf2, const float* __restrict__ ln1,
                const float* __restrict__ g, const float* __restrict__ beta,
                float* __restrict__ out) {
    const int tid = threadIdx.x;
    const int w = tid >> 6, l = tid & 63;
    const int l15 = l & 15, lg = l >> 4;
    const int mr = blockIdx.x * 16;
    const int n0 = w * 64;

    f32x4 acc[4] = {};
    const bf16* a0 = &h1[(size_t)(mr + l15) * 1024 + lg * 8];
    const bf16* b0 = &W2T[(size_t)(n0 + l15) * 1024 + lg * 8];
    for (int k0 = 0; k0 < 1024; k0 += 32) {
        bf16x8 a = *reinterpret_cast<const bf16x8*>(a0 + k0);
        #pragma unroll
        for (int j = 0; j < 4; ++j) {
            bf16x8 b = *reinterpret_cast<const bf16x8*>(b0 + (size_t)j * 16 * 1024 + k0);
            acc[j] = __builtin_amdgcn_mfma_f32_16x16x32_bf16(a, b, acc[j], 0, 0, 0);
        }
    }

    float val[4][4];
    float rsum[4] = {0.f, 0.f, 0.f, 0.f}, rsq[4] = {0.f, 0.f, 0.f, 0.f};
    #pragma unroll
    for (int j = 0; j < 4; ++j) {
        const int col = n0 + j * 16 + l15;
        const float bs = bf2[col];
        #pragma unroll
        for (int r = 0; r < 4; ++r) {
            const int row = mr + lg * 4 + r;
            float v = acc[j][r] + bs + ln1[(size_t)row * CCH + col];
            val[j][r] = v;
            rsum[r] += v;
            rsq[r] += v * v;
        }
    }
    #pragma unroll
    for (int r = 0; r < 4; ++r) {
        #pragma unroll
        for (int off = 1; off < 16; off <<= 1) {
            rsum[r] += __shfl_xor(rsum[r], off);
            rsq[r]  += __shfl_xor(rsq[r], off);
        }
    }
    __shared__ float ssum[4][16], ssq[4][16];
    if (l15 == 0) {
        #pragma unroll
        for (int r = 0; r < 4; ++r) {
            ssum[w][lg * 4 + r] = rsum[r];
            ssq[w][lg * 4 + r]  = rsq[r];
        }
    }
    __syncthreads();
    float mu_[4], rs_[4];
    #pragma unroll
    for (int r = 0; r < 4; ++r) {
        const int row = lg * 4 + r;
        float s = (ssum[0][row] + ssum[1][row]) + (ssum[2][row] + ssum[3][row]);
        float q = (ssq[0][row] + ssq[1][row]) + (ssq[2][row] + ssq[3][row]);
        float mu = s * (1.0f / CCH);
        float var = q * (1.0f / CCH) - mu * mu;
        mu_[r] = mu;
        rs_[r] = rsqrtf(var + LN_EPS);
    }

    __shared__ float tile[256][17];
    #pragma unroll
    for (int j = 0; j < 4; ++j) {
        const int col = n0 + j * 16 + l15;
        const float gg = g[col], bb = beta[col];
        #pragma unroll
        for (int r = 0; r < 4; ++r)
            tile[col][lg * 4 + r] = (val[j][r] - mu_[r]) * rs_[r] * gg + bb;
    }
    __syncthreads();
    // write out[c][mr..mr+16): 64B contiguous per thread
    const int c = tid;
    float* orow = &out[(size_t)c * SQ + mr];
    #pragma unroll
    for (int q4 = 0; q4 < 4; ++q4) {
        float4 o4 = {tile[c][q4 * 4], tile[c][q4 * 4 + 1],
                     tile[c][q4 * 4 + 2], tile[c][q4 * 4 + 3]};
        *reinterpret_cast<float4*>(orow + q4 * 4) = o4;
    }
}

// ---------------------------------------------------------------------------
// MFMA flash attention v11 (unchanged): quad-Q, swapped QK^T, no-max softmax,
// MFMA row-sum via ones-row, raw v_exp_f32.
// ---------------------------------------------------------------------------
__global__ __launch_bounds__(256)
void flash_attn11(const bf16* __restrict__ qb, const bf16* __restrict__ kb,
                  const bf16* __restrict__ vT, bf16* __restrict__ Op,
                  float* __restrict__ Lp) {
    const int fid = blockIdx.x + 16 * (blockIdx.y + NH * blockIdx.z);
    const int nid = (fid & 7) * 64 + (fid >> 3);
    const int q0 = (nid & 15) * 256;
    const int h  = (nid >> 4) & 7;
    const int sp = nid >> 7;

    const int tid = threadIdx.x;
    const int w = tid >> 6, l = tid & 63;
    const int l15 = l & 15, lg = l >> 4;

    __shared__ unsigned int Sb[4][2][8][72];   // [wave][parity][slot][lane] 18KB

    bf16x8 aq[4];
    #pragma unroll
    for (int su = 0; su < 4; ++su)
        aq[su] = *reinterpret_cast<const bf16x8*>(
            &qb[(size_t)(q0 + su * 64 + w * 16 + l15) * CCH + h * HD + lg * 8]);

    f32x4 o[4][2] = {};
    f32x4 o2[4] = {};   // row-sum accumulators (ones-row MFMA)

    const bf16* kfrag = &kb[(size_t)l15 * CCH + h * HD + lg * 8];
    const bf16* vfrag = &vT[((size_t)h * VROWS + l15) * SQ + lg * 8];

    const int kt0 = sp * (SQ / NSPLIT / 64);
    const int kt1 = kt0 + (SQ / NSPLIT / 64);

    for (int kt = kt0; kt < kt1; ++kt) {
        const int kb0 = kt * 64;

        bf16x8 kf[4], vf[3][2];
        #pragma unroll
        for (int t = 0; t < 4; ++t)
            kf[t] = *reinterpret_cast<const bf16x8*>(kfrag + (size_t)(kb0 + t * 16) * CCH);
        #pragma unroll
        for (int dh = 0; dh < 3; ++dh)
            #pragma unroll
            for (int kh = 0; kh < 2; ++kh)
                vf[dh][kh] = *reinterpret_cast<const bf16x8*>(
                    vfrag + (size_t)dh * 16 * SQ + kb0 + kh * 32);

        #pragma unroll
        for (int su = 0; su < 4; ++su) {
            const int par = su & 1;
            f32x4 s[4];
            #pragma unroll
            for (int t = 0; t < 4; ++t)
                s[t] = __builtin_amdgcn_mfma_f32_16x16x32_bf16(
                    kf[t], aq[su], (f32x4){0.f, 0.f, 0.f, 0.f}, 0, 0, 0);

            #pragma unroll
            for (int t = 0; t < 4; ++t) {
                unsigned int u0 = __builtin_bit_cast(unsigned int, fast_exp2(s[t][0]));
                unsigned int u1 = __builtin_bit_cast(unsigned int, fast_exp2(s[t][1]));
                unsigned int u2 = __builtin_bit_cast(unsigned int, fast_exp2(s[t][2]));
                unsigned int u3 = __builtin_bit_cast(unsigned int, fast_exp2(s[t][3]));
                Sb[w][par][t * 2 + 0][l] = __builtin_amdgcn_perm(u1, u0, 0x07060302u);
                Sb[w][par][t * 2 + 1][l] = __builtin_amdgcn_perm(u3, u2, 0x07060302u);
            }

            #pragma unroll
            for (int kh = 0; kh < 2; ++kh) {
                const int sbase = kh * 4 + (lg >> 1) * 2;
                const int i0 = l15 + 16 * ((lg & 1) * 2);
                const int i1 = i0 + 16;
                union { unsigned int u[4]; bf16x8 v; } pb;
                pb.u[0] = Sb[w][par][sbase + 0][i0];
                pb.u[1] = Sb[w][par][sbase + 1][i0];
                pb.u[2] = Sb[w][par][sbase + 0][i1];
                pb.u[3] = Sb[w][par][sbase + 1][i1];
                #pragma unroll
                for (int dh = 0; dh < 2; ++dh)
                    o[su][dh] = __builtin_amdgcn_mfma_f32_16x16x32_bf16(
                        vf[dh][kh], pb.v, o[su][dh], 0, 0, 0);
                o2[su] = __builtin_amdgcn_mfma_f32_16x16x32_bf16(
                    vf[2][kh], pb.v, o2[su], 0, 0, 0);
            }
        }
    }

    const size_t obase = ((size_t)sp * NH + h) * HD;
    #pragma unroll
    for (int su = 0; su < 4; ++su) {
        const int qrow = q0 + su * 64 + w * 16 + l15;
        #pragma unroll
        for (int dh = 0; dh < 2; ++dh)
            #pragma unroll
            for (int r = 0; r < 4; ++r)
                Op[(obase + dh * 16 + lg * 4 + r) * SQ + qrow] = (bf16)o[su][dh][r];
        if (lg == 0)
            Lp[((size_t)sp * NH + h) * SQ + qrow] = o2[su][0];
    }
}

// ---------------------------------------------------------------------------
// Merge NSPLIT raw partial O^T [d][q] tiles -> atb [S][C] bf16.
// ---------------------------------------------------------------------------
__global__ __launch_bounds__(256)
void attn_merge3(const bf16* __restrict__ Op, const float* __restrict__ Lp,
                 bf16* __restrict__ atb) {
    const int h = blockIdx.y;
    const int q0 = blockIdx.x * 64;
    const int t = threadIdx.x;
    __shared__ float sInv[64];
    __shared__ float trans[32][65];

    if (t < 64) {
        float L = 0.f;
        #pragma unroll
        for (int sp = 0; sp < NSPLIT; ++sp)
            L += Lp[((size_t)sp * NH + h) * SQ + q0 + t];
        sInv[t] = 1.0f / L;
    }
    __syncthreads();

    const int q = t & 63, dg = t >> 6;
    float a[8] = {0.f, 0.f, 0.f, 0.f, 0.f, 0.f, 0.f, 0.f};
    for (int sp = 0; sp < NSPLIT; ++sp) {
        const size_t rb = ((size_t)sp * NH + h) * HD;
        #pragma unroll
        for (int i = 0; i < 8; ++i) {
            const int d = i * 4 + dg;
            a[i] += (float)Op[(rb + d) * SQ + q0 + q];
        }
    }
    const float invq = sInv[q];
    #pragma unroll
    for (int i = 0; i < 8; ++i)
        trans[i * 4 + dg][q] = a[i] * invq;
    __syncthreads();

    const int oq = t >> 2, od = (t & 3) * 8;
    bf16x8 o8;
    #pragma unroll
    for (int j = 0; j < 8; ++j) o8[j] = (bf16)trans[od + j][oq];
    *reinterpret_cast<bf16x8*>(&atb[(size_t)(q0 + oq) * CCH + h * HD + od]) = o8;
}

// ---------------------------------------------------------------------------
extern "C" void kernel_launch(void* const* d_in, const int* in_sizes, int n_in,
                              void* d_out, int out_size, void* d_ws, size_t ws_size,
                              hipStream_t stream) {
    const float* lidar = (const float*)d_in[0];
    const float* image = (const float*)d_in[1];
    const float* Wq  = (const float*)d_in[2];
    const float* bq  = (const float*)d_in[3];
    const float* Wk  = (const float*)d_in[4];
    const float* bk  = (const float*)d_in[5];
    const float* Wv  = (const float*)d_in[6];
    const float* bv  = (const float*)d_in[7];
    const float* Wo  = (const float*)d_in[8];
    const float* bo  = (const float*)d_in[9];
    const float* g1  = (const float*)d_in[10];
    const float* b1  = (const float*)d_in[11];
    const float* W1  = (const float*)d_in[12];
    const float* bf1 = (const float*)d_in[13];
    const float* W2  = (const float*)d_in[14];
    const float* bf2 = (const float*)d_in[15];
    const float* g2  = (const float*)d_in[16];
    const float* b2  = (const float*)d_in[17];
    float* out = (float*)d_out;

    // workspace layout (aliased; peak 23.5 MB).  Lp (512K) in d_out until merge.
    char* ws = (char*)d_ws;
    const size_t KB = 1024;
    bf16* W2T = (bf16*)(ws + 0);                 // [0,512K)     live -> ffn2_ln2_t
    bf16* W1T = (bf16*)(ws + 512 * KB);          // [512K,1M)    live -> ffn1
    bf16* WoT = (bf16*)(ws + 1024 * KB);         // [1,1.125M)   live -> wo_ln1
    bf16* WqT = (bf16*)(ws + 1152 * KB);         // dead after qkv
    bf16* WkT = (bf16*)(ws + 1280 * KB);
    bf16* WvT = (bf16*)(ws + 1408 * KB);         // ends 1.5M
    bf16* qb  = (bf16*)(ws + 1536 * KB);         // [1.5,3.5M)   live -> wo_ln1
    bf16* kbb = (bf16*)(ws + 3584 * KB);         // [3.5,5.5M)   dead after flash
    bf16* vTb = (bf16*)(ws + 5632 * KB);         // [5.5,8.5M)   padded; dead after flash
    bf16* xT  = (bf16*)(ws + 8704 * KB);         // [8.5,10.5M)  dead after qkv
    bf16* yT  = (bf16*)(ws + 10752 * KB);        // [10.5,12.5M) dead after qkv
    bf16* Op  = (bf16*)(ws + 8704 * KB);         // [8.5,16.5M)  overlays xT/yT
    float* Lp = (float*)d_out;                   // 512K scratch in d_out
    bf16* atb = (bf16*)(ws + 3584 * KB);         // reuses kbb; dead after wo_ln1
    float* ln1 = (float*)(ws + 19968 * KB);      // [19.5,23.5M) live -> ffn2_ln2_t
    bf16* ln1b = (bf16*)(ws + 5632 * KB);        // [5.5,7.5M)   reuses vTb; dead after ffn1
    bf16* h1  = (bf16*)(ws + 9728 * KB);         // [9.5,17.5M)  dead after ffn2_ln2_t

    // 1/sqrt(32) * log2(e) folded into K -> scores already in log2 domain
    const float qscale = 0.17677669529663687f * 1.4426950408889634f;
    dim3 blk(256);

    // all layout conversions in one launch
    cvt_all<<<dim3(2880), blk, 0, stream>>>(lidar, image, xT, yT,
                                            Wq, Wk, Wv, Wo, W1, W2,
                                            WqT, WkT, WvT, WoT, W1T, W2T, vTb);
    // fused QKV projections
    qkv_gemm<<<dim3(64, 4, 3), blk, 0, stream>>>(xT, yT, WqT, WkT, WvT,
                                                 bq, bk, bv, qb, kbb, vTb, qscale);
    // attention (split-KV x4, swapped-operand, no-max, MFMA row-sum, v_exp)
    flash_attn11<<<dim3(SQ / 256, NH, NSPLIT), blk, 0, stream>>>(qb, kbb, vTb, Op, Lp);
    attn_merge3<<<dim3(SQ / 64, NH), blk, 0, stream>>>(Op, Lp, atb);
    // fused Wo projection + residual + LN1 (row-panel)
    wo_ln1<<<dim3(SQ / 16), blk, 0, stream>>>(atb, WoT, bo, qb, g1, b1, ln1, ln1b);
    // FFN1
    gemm_mfma<256, 2, true><<<dim3(64, 16), blk, 0, stream>>>(ln1b, W1T, bf1, nullptr, h1, 1024);
    // fused FFN2 + residual + LN2 + transpose (row-panel)
    ffn2_ln2_t<<<dim3(SQ / 16), blk, 0, stream>>>(h1, W2T, bf2, ln1, g2, b2, out);
}